// Round 24
// baseline (355.025 us; speedup 1.0000x reference)
//
#include <hip/hip_runtime.h>
#include <math.h>

#define B_   32
#define N_   1024
#define C_   4096
#define HC_  2048
#define D_   64
#define NT_  32768           // B*N tokens
#define BKC_ 128             // K-chunk per staging step (deep streaming)
#define NCH_ (HC_ / BKC_)    // 16 chunks
#define AST_ 68              // As row stride (64 rows + 4 pad)

__device__ __forceinline__ float4 ld4(const float* p) {
    return *reinterpret_cast<const float4*>(p);
}

// global -> LDS direct DMA, 16 B per lane (dest = uniform base + lane*16)
#define GLDS16(g, l)                                                        \
    __builtin_amdgcn_global_load_lds(                                       \
        (const __attribute__((address_space(1))) unsigned int*)(g),         \
        (__attribute__((address_space(3))) unsigned int*)(l), 16, 0, 0)

// ---------------------------------------------------------------------------
// K0w: prefold w'[k][d] = lnw[k] * w1[k][d]  (f32, exact; same products as
// the in-kernel folding -> bitwise-identical P).  grid 128, block 256.
// ---------------------------------------------------------------------------
__global__ __launch_bounds__(256) void k0w_prep(
        const float* __restrict__ lnw, const float* __restrict__ w1,
        float* __restrict__ wf) {
    const int idx = blockIdx.x * 256 + threadIdx.x;   // float4 index
    float4 v = reinterpret_cast<const float4*>(w1)[idx];
    const float s = lnw[idx >> 4];                    // k = idx/16 (D=64)
    v.x *= s; v.y *= s; v.z *= s; v.w *= s;
    reinterpret_cast<float4*>(wf)[idx] = v;
}

// ---------------------------------------------------------------------------
// MK1 v9: r21 champion + B-staging via global_load_lds (width 16).
// grid 512 (M64 tiles), block 256.
// G: 8r x 8d thread tile (acc[64]), k-split across waves, deep A staging
//    (8 consecutive b128/thread); B staged by direct DMA from prefolded w'
//    (L2-resident) -> no VGPR round-trip, ~40 regs freed.
// U: r21-verbatim.  LDS 67.6 KB union -> 2 blocks/CU.
// ---------------------------------------------------------------------------
__global__ __launch_bounds__(256) void mk1(
        const float* __restrict__ x, const float* __restrict__ lnw,
        const float* __restrict__ lnb, const float* __restrict__ wf,
        float* __restrict__ Pp, float* __restrict__ muv,
        float* __restrict__ rsv, float* __restrict__ part) {
    __shared__ float smem[16896];      // 67.6 KB union
    __shared__ float sLow[64], qLow[64];
    float* As = smem;                  // [128][68] k-major
    float* Bsm = smem + 8704;          // [128][64]

    const int t = threadIdx.x;
    const int tid = blockIdx.x;
    const int T0 = tid * 64;
    const int row = t >> 2;            // staging row (0..63)
    const int fq = t & 3;              // staging k-block (32 cols each)
    const int lane = t & 63, w = t >> 6;
    const int rt = lane >> 3, dt = lane & 7;   // 8x8 FMA tile coords

    // ===================== Phase G: GEMM + lower stats =====================
    float acc[64];
#pragma unroll
    for (int i = 0; i < 64; ++i) acc[i] = 0.f;
    float sR = 0.f, qR = 0.f;

    float4 xv[8];                      // x[T0+row][k0+fq*32 .. +31]
    {   // prologue: chunk-0 A loads (8 independent b128 in flight)
        const float* rp = x + (size_t)(T0 + row) * C_ + fq * 32;
#pragma unroll
        for (int i = 0; i < 8; ++i) xv[i] = ld4(rp + i * 4);
    }

#pragma unroll 1
    for (int c = 0; c < NCH_; ++c) {
        // ---- B staging: direct DMA from prefolded w' (L2-hot) ----
        {
            const float* wsrc = wf + (size_t)c * BKC_ * D_;
#pragma unroll
            for (int i = 0; i < 8; ++i)
                GLDS16(wsrc + (i * 256 + w * 64 + lane) * 4,
                       Bsm + i * 1024 + w * 256);
        }
        // ---- stage A (k-major, stride 68) + stats from regs ----
#pragma unroll
        for (int i = 0; i < 8; ++i) {
            const float4 v = xv[i];
            const int kl = fq * 32 + i * 4;
            As[(kl + 0) * AST_ + row] = v.x;
            As[(kl + 1) * AST_ + row] = v.y;
            As[(kl + 2) * AST_ + row] = v.z;
            As[(kl + 3) * AST_ + row] = v.w;
            sR += (v.x + v.y) + (v.z + v.w);
            qR = fmaf(v.x, v.x, fmaf(v.y, v.y,
                 fmaf(v.z, v.z, fmaf(v.w, v.w, qR))));
        }
        __syncthreads();   // drains vmcnt (incl. global_load_lds) + lgkm
        // ---- prefetch chunk c+1 A (8 independent b128s, overlap FMA) ----
        if (c + 1 < NCH_) {
            const int k1 = (c + 1) * BKC_;
            const float* rp = x + (size_t)(T0 + row) * C_ + k1 + fq * 32;
#pragma unroll
            for (int i = 0; i < 8; ++i) xv[i] = ld4(rp + i * 4);
        }
        // ---- FMA: wave w handles its 32-k quarter; 4 b128 per 64 FMA ----
#pragma unroll 8
        for (int kk = 0; kk < 32; ++kk) {
            const int k = w * 32 + kk;
            const float4 a0 = *reinterpret_cast<const float4*>(
                As + k * AST_ + rt * 8);
            const float4 a1 = *reinterpret_cast<const float4*>(
                As + k * AST_ + rt * 8 + 4);
            const float4 b0 = *reinterpret_cast<const float4*>(
                Bsm + k * 64 + dt * 8);
            const float4 b1 = *reinterpret_cast<const float4*>(
                Bsm + k * 64 + dt * 8 + 4);
            const float av[8] = {a0.x, a0.y, a0.z, a0.w,
                                 a1.x, a1.y, a1.z, a1.w};
            const float bv[8] = {b0.x, b0.y, b0.z, b0.w,
                                 b1.x, b1.y, b1.z, b1.w};
#pragma unroll
            for (int ri = 0; ri < 8; ++ri)
#pragma unroll
                for (int cj = 0; cj < 8; ++cj)
                    acc[ri * 8 + cj] =
                        fmaf(av[ri], bv[cj], acc[ri * 8 + cj]);
        }
        __syncthreads();
    }
    // ---- lower-stats reduce: 4 staging threads per row ----
    sR += __shfl_xor(sR, 1); qR += __shfl_xor(qR, 1);
    sR += __shfl_xor(sR, 2); qR += __shfl_xor(qR, 2);
    if (fq == 0) { sLow[row] = sR; qLow[row] = qR; }

    // ---- cross-wave acc reduce via smem (As/Bsm dead) + P write ----
#pragma unroll
    for (int i = 0; i < 64; ++i) smem[i * 256 + t] = acc[i];
    __syncthreads();
#pragma unroll
    for (int r2 = 0; r2 < 2; ++r2) {
        const int rowO = rt * 8 + w * 2 + r2;
        float v[8];
#pragma unroll
        for (int cj = 0; cj < 8; ++cj) {
            const int i = w * 16 + r2 * 8 + cj;
            v[cj] = (smem[i * 256 + lane]
                     + smem[i * 256 + 64 + lane])
                  + (smem[i * 256 + 128 + lane]
                     + smem[i * 256 + 192 + lane]);
        }
        float* dst = Pp + (size_t)(T0 + rowO) * D_ + dt * 8;
        *reinterpret_cast<float4*>(dst) =
            make_float4(v[0], v[1], v[2], v[3]);
        *reinterpret_cast<float4*>(dst + 4) =
            make_float4(v[4], v[5], v[6], v[7]);
    }
    __syncthreads();

    // ===================== Phase U: upper stats + g-accum ==================
    float4 wvu[8], bvu[8], gacc[8];
#pragma unroll
    for (int m = 0; m < 8; ++m) {
        wvu[m] = ld4(lnw + HC_ + (m * 64 + lane) * 4);
        bvu[m] = ld4(lnb + HC_ + (m * 64 + lane) * 4);
        gacc[m] = make_float4(0.f, 0.f, 0.f, 0.f);
    }
    for (int i = 0; i < 16; ++i) {
        const int r = w * 16 + i;
        const int tok = T0 + r;
        const float* rowp = x + (size_t)tok * C_ + HC_;
        float4 v[8];
        float s = 0.f, q = 0.f;
#pragma unroll
        for (int m = 0; m < 8; ++m) {
            v[m] = ld4(rowp + (m * 64 + lane) * 4);
            s += (v[m].x + v[m].y) + (v[m].z + v[m].w);
            q = fmaf(v[m].x, v[m].x, fmaf(v[m].y, v[m].y,
                fmaf(v[m].z, v[m].z, fmaf(v[m].w, v[m].w, q))));
        }
#pragma unroll
        for (int o = 1; o < 64; o <<= 1) {
            s += __shfl_xor(s, o);
            q += __shfl_xor(q, o);
        }
        const float S_ = s + sLow[r];
        const float Q_ = q + qLow[r];
        const float mu = S_ * (1.f / C_);
        const float rs = rsqrtf(Q_ * (1.f / C_) - mu * mu + 1e-5f);
        if (lane == 0) {
            muv[tok] = mu;
            rsv[tok] = rs;
        }
#pragma unroll
        for (int m = 0; m < 8; ++m) {
            gacc[m].x += (v[m].x - mu) * rs * wvu[m].x + bvu[m].x;
            gacc[m].y += (v[m].y - mu) * rs * wvu[m].y + bvu[m].y;
            gacc[m].z += (v[m].z - mu) * rs * wvu[m].z + bvu[m].z;
            gacc[m].w += (v[m].w - mu) * rs * wvu[m].w + bvu[m].w;
        }
    }
    // cross-wave reduction via smem (sh[4][2048])
    float (*sh)[HC_] = reinterpret_cast<float(*)[HC_]>(smem);
    __syncthreads();
#pragma unroll
    for (int m = 0; m < 8; ++m)
        *reinterpret_cast<float4*>(&sh[w][(m * 64 + lane) * 4]) = gacc[m];
    __syncthreads();
    float* pp = part + (size_t)tid * HC_;
#pragma unroll
    for (int m = 0; m < 8; ++m) {
        const int j = (m * 64 + lane) * 4;
        const float4 a0 = ld4(&sh[0][j]);
        const float4 a1 = ld4(&sh[1][j]);
        const float4 a2 = ld4(&sh[2][j]);
        const float4 a3 = ld4(&sh[3][j]);
        float4 r;
        r.x = (a0.x + a1.x) + (a2.x + a3.x);
        r.y = (a0.y + a1.y) + (a2.y + a3.y);
        r.z = (a0.z + a1.z) + (a2.z + a3.z);
        r.w = (a0.w + a1.w) + (a2.w + a3.w);
        if (w == (m & 3))    // spread the 8 stores across the 4 waves
            *reinterpret_cast<float4*>(pp + j) = r;
    }
}

// ---------------------------------------------------------------------------
// K2a: fold partial-reduce + partial GEMVs.  grid 264, block 256.
// ---------------------------------------------------------------------------
__global__ __launch_bounds__(256) void k2a_part(
        const float* __restrict__ part, const float* __restrict__ w1,
        const float* __restrict__ lnw, const float* __restrict__ lnb,
        float* __restrict__ gpart, float* __restrict__ Wpart,
        float* __restrict__ Bpart) {
    __shared__ float Gs[256];
    __shared__ float red[512];
    const int t = threadIdx.x;
    const int d = t & 63, s = t >> 6;
    const int blk = blockIdx.x;
    if (blk < 256) {
        const int b = blk >> 3, jq = blk & 7;
        const int j = jq * 256 + t;
        float a = 0.f;
        for (int k = 0; k < 16; ++k)
            a += part[(size_t)(b * 16 + k) * HC_ + j];
        Gs[t] = a;
        __syncthreads();
        float acc = 0.f;
        const int j0 = jq * 256 + s * 64;
        for (int jj = 0; jj < 64; ++jj)
            acc = fmaf(Gs[s * 64 + jj],
                       w1[(size_t)(HC_ + j0 + jj) * D_ + d], acc);
        red[s * 64 + d] = acc;
        __syncthreads();
        if (s == 0)
            gpart[(size_t)blk * 64 + d] =
                red[d] + red[64 + d] + red[128 + d] + red[192 + d];
    } else {
        const int wq = blk - 256;
        const int c0 = wq * 256 + s * 64;
        float a = 0.f, c2 = 0.f;
        for (int c = c0; c < c0 + 64; ++c) {
            const float wvv = w1[(size_t)c * D_ + d];
            a = fmaf(lnw[c], wvv, a);
            c2 = fmaf(lnb[c], wvv, c2);
        }
        red[s * 64 + d] = a;
        red[256 + s * 64 + d] = c2;
        __syncthreads();
        if (s == 0) {
            Wpart[wq * 64 + d] =
                red[d] + red[64 + d] + red[128 + d] + red[192 + d];
            Bpart[wq * 64 + d] = red[256 + d] + red[320 + d]
                               + red[384 + d] + red[448 + d];
        }
    }
}

// ---------------------------------------------------------------------------
// K45: decision (k2b folded) + masked copy.  One wave per token.
// Dropped tokens write zeros WITHOUT reading x.  grid 8192, block 256.
// ---------------------------------------------------------------------------
__global__ __launch_bounds__(256) void k45_decide_mask(
        const float* __restrict__ Pp, const float* __restrict__ muv,
        const float* __restrict__ rsv, const float* __restrict__ gpart,
        const float* __restrict__ Wpart, const float* __restrict__ Bpart,
        const float* __restrict__ b1, const float* __restrict__ w2,
        const float* __restrict__ b2, const float* __restrict__ gum,
        const float* __restrict__ x, float* __restrict__ out) {
    const int t = threadIdx.x;
    const int lane = t & 63, w = t >> 6;
    const int token = blockIdx.x * 4 + w;
    const int b = token >> 10;

    // ---- folded k2b: W1s/Bs/gterm for this lane (L2-hot) ----
    float W1 = 0.f, Bsv = 0.f, gt = 0.f;
#pragma unroll
    for (int q = 0; q < 8; ++q) {
        W1 += Wpart[q * 64 + lane];
        Bsv += Bpart[q * 64 + lane];
        gt += gpart[(size_t)(b * 8 + q) * 64 + lane];
    }
    gt *= (1.f / N_);

    const float2 gv = *reinterpret_cast<const float2*>(gum + token * 2);
    const float p = Pp[(size_t)token * D_ + lane];
    const float mu = muv[token], rs = rsv[token];
    float h = rs * (p - mu * W1) + Bsv + gt + b1[lane];
    h = 0.5f * h * (1.f + erff(h * 0.70710678118654752f));   // exact gelu
    const float2 w2v = *reinterpret_cast<const float2*>(w2 + lane * 2);
    float l0 = h * w2v.x;
    float l1 = h * w2v.y;
#pragma unroll
    for (int o = 1; o < 64; o <<= 1) {
        l0 += __shfl_xor(l0, o);
        l1 += __shfl_xor(l1, o);
    }
    const float z0 = l0 + b2[0] + gv.x;
    const float z1 = l1 + b2[1] + gv.y;

    float4* dst = reinterpret_cast<float4*>(out + (size_t)token * C_);
    if (z0 >= z1) {    // keep (argmax ties -> index 0): copy x
        const float4* src =
            reinterpret_cast<const float4*>(x + (size_t)token * C_);
#pragma unroll
        for (int c = 0; c < 16; ++c)
            dst[c * 64 + lane] = src[c * 64 + lane];
    } else {           // drop: write zeros, skip the x read
        const float4 z = make_float4(0.f, 0.f, 0.f, 0.f);
#pragma unroll
        for (int c = 0; c < 16; ++c)
            dst[c * 64 + lane] = z;
    }
}

// ---------------------------------------------------------------------------
extern "C" void kernel_launch(void* const* d_in, const int* in_sizes, int n_in,
                              void* d_out, int out_size, void* d_ws,
                              size_t ws_size, hipStream_t stream) {
    const float* x   = (const float*)d_in[0];
    const float* gum = (const float*)d_in[1];
    const float* lnw = (const float*)d_in[2];
    const float* lnb = (const float*)d_in[3];
    const float* w1  = (const float*)d_in[4];
    const float* b1  = (const float*)d_in[5];
    const float* w2  = (const float*)d_in[6];
    const float* b2  = (const float*)d_in[7];
    float* out = (float*)d_out;

    float* wsf   = (float*)d_ws;
    float* Pp    = wsf;                                   // 32768*64
    float* muv   = Pp + (size_t)NT_ * D_;                 // 32768
    float* rsv   = muv + NT_;                             // 32768
    float* part  = rsv + NT_;                             // 512*2048
    float* gpart = part + (size_t)512 * HC_;              // 256*64
    float* Wpart = gpart + 256 * 64;                      // 8*64
    float* Bpart = Wpart + 8 * 64;                        // 8*64
    float* wf    = Bpart + 8 * 64;                        // 2048*64 prefold

    k0w_prep<<<128, 256, 0, stream>>>(lnw, w1, wf);
    mk1<<<512, 256, 0, stream>>>(x, lnw, lnb, wf, Pp, muv, rsv, part);
    k2a_part<<<264, 256, 0, stream>>>(part, w1, lnw, lnb,
                                      gpart, Wpart, Bpart);
    k45_decide_mask<<<NT_ / 4, 256, 0, stream>>>(Pp, muv, rsv, gpart,
                                                 Wpart, Bpart, b1, w2, b2,
                                                 gum, x, out);
}

// Round 25
// 336.829 us; speedup vs baseline: 1.0540x; 1.0540x over previous
//
#include <hip/hip_runtime.h>
#include <math.h>

#define B_   32
#define N_   1024
#define C_   4096
#define HC_  2048
#define D_   64
#define NT_  32768           // B*N tokens
#define BKC_ 64              // K-chunk (double-buffered)
#define NCH_ (HC_ / BKC_)    // 32 chunks
#define AST_ 68              // As row stride (64 rows + 4 pad)
#define BUF_ 8448            // floats per LDS buffer (As 4352 + Bs 4096)

__device__ __forceinline__ float4 ld4(const float* p) {
    return *reinterpret_cast<const float4*>(p);
}

// ---------------------------------------------------------------------------
// MK1 v10: fused vector GEMM (exact f32) + LN stats + upper g-accum,
// with TRUE LDS DOUBLE-BUFFERING in phase G.
// grid 512 (M64 tiles), block 256.
// Per iteration: FMA(c) from buf[c&1]  ||  ds_write(c+1)->buf[(c+1)&1]
// (+stats)  ||  issue global loads(c+2); then ONE barrier.  Staging is no
// longer serialized before FMA (was ~25-35us of mk1's 186us); dbuf gives a
// full-iteration (~2000cy) latency cover so BKC=64 staging depth suffices.
// G tiles: 8r x 8d (acc[64]), k-split across waves (wave w owns
// k in [w*16,(w+1)*16) of each 64-chunk).  Chunk order identical to the
// champion -> bitwise-identical output.
// LDS 67.6 KB (2 x 33.1 KB buffers) -> 2 blocks/CU.  Phase U: r21-verbatim.
// ---------------------------------------------------------------------------
__global__ __launch_bounds__(256) void mk1(
        const float* __restrict__ x, const float* __restrict__ lnw,
        const float* __restrict__ lnb, const float* __restrict__ w1,
        float* __restrict__ Pp, float* __restrict__ muv,
        float* __restrict__ rsv, float* __restrict__ part) {
    __shared__ float smem[16896];      // 67.6 KB: 2 x (As[64][68]+Bs[64][64])
    __shared__ float sLow[64], qLow[64];

    const int t = threadIdx.x;
    const int tid = blockIdx.x;
    const int T0 = tid * 64;
    const int row = t >> 2;            // staging row (0..63)
    const int fq = t & 3;              // staging k-block (16 cols each)
    const int lane = t & 63, w = t >> 6;
    const int rt = lane >> 3, dt = lane & 7;   // 8x8 FMA tile coords

    // ===================== Phase G: GEMM + lower stats =====================
    float acc[64];
#pragma unroll
    for (int i = 0; i < 64; ++i) acc[i] = 0.f;
    float sR = 0.f, qR = 0.f;

    float4 xv[4];                      // next-chunk x regs
    float4 wv[4];                      // next-chunk w1 regs
    float lw[4];

    {   // prologue: load chunk 0; stage chunk 0 -> buf0; load chunk 1
        const float* rp = x + (size_t)(T0 + row) * C_ + fq * 16;
#pragma unroll
        for (int i = 0; i < 4; ++i) xv[i] = ld4(rp + i * 4);
        const float4* s4 = reinterpret_cast<const float4*>(w1);
#pragma unroll
        for (int i = 0; i < 4; ++i) {
            wv[i] = s4[i * 256 + t];
            lw[i] = lnw[(i * 256 + t) >> 4];
        }
        float* A0 = smem;
        float* B0 = smem + 4352;
#pragma unroll
        for (int i = 0; i < 4; ++i) {
            const float4 v = xv[i];
            const int kl = fq * 16 + i * 4;
            A0[(kl + 0) * AST_ + row] = v.x;
            A0[(kl + 1) * AST_ + row] = v.y;
            A0[(kl + 2) * AST_ + row] = v.z;
            A0[(kl + 3) * AST_ + row] = v.w;
            sR += (v.x + v.y) + (v.z + v.w);
            qR = fmaf(v.x, v.x, fmaf(v.y, v.y,
                 fmaf(v.z, v.z, fmaf(v.w, v.w, qR))));
        }
        {
            float4* b4 = reinterpret_cast<float4*>(B0);
#pragma unroll
            for (int i = 0; i < 4; ++i) {
                float4 v = wv[i];
                v.x *= lw[i]; v.y *= lw[i]; v.z *= lw[i]; v.w *= lw[i];
                b4[i * 256 + t] = v;
            }
        }
        // load chunk 1 regs
        const float* rp1 = x + (size_t)(T0 + row) * C_ + BKC_ + fq * 16;
#pragma unroll
        for (int i = 0; i < 4; ++i) xv[i] = ld4(rp1 + i * 4);
        const float4* s41 = reinterpret_cast<const float4*>(
            w1 + (size_t)BKC_ * D_);
#pragma unroll
        for (int i = 0; i < 4; ++i) {
            wv[i] = s41[i * 256 + t];
            lw[i] = lnw[BKC_ + ((i * 256 + t) >> 4)];
        }
        __syncthreads();
    }

#pragma unroll 1
    for (int c = 0; c < NCH_; ++c) {
        float* Acur = smem + (c & 1) * BUF_;
        float* Bcur = Acur + 4352;
        float* Anxt = smem + ((c + 1) & 1) * BUF_;
        float* Bnxt = Anxt + 4352;

        // ---- FMA(c): wave w owns its 16-k quarter; 4 b128 per 64 FMA ----
#pragma unroll 8
        for (int kk = 0; kk < 16; ++kk) {
            const int k = w * 16 + kk;
            const float4 a0 = *reinterpret_cast<const float4*>(
                Acur + k * AST_ + rt * 8);
            const float4 a1 = *reinterpret_cast<const float4*>(
                Acur + k * AST_ + rt * 8 + 4);
            const float4 b0 = *reinterpret_cast<const float4*>(
                Bcur + k * 64 + dt * 8);
            const float4 b1 = *reinterpret_cast<const float4*>(
                Bcur + k * 64 + dt * 8 + 4);
            const float av[8] = {a0.x, a0.y, a0.z, a0.w,
                                 a1.x, a1.y, a1.z, a1.w};
            const float bv[8] = {b0.x, b0.y, b0.z, b0.w,
                                 b1.x, b1.y, b1.z, b1.w};
#pragma unroll
            for (int ri = 0; ri < 8; ++ri)
#pragma unroll
                for (int cj = 0; cj < 8; ++cj)
                    acc[ri * 8 + cj] =
                        fmaf(av[ri], bv[cj], acc[ri * 8 + cj]);
        }
        // ---- ds_write chunk c+1 -> other buffer (+stats) ----
        if (c + 1 < NCH_) {
#pragma unroll
            for (int i = 0; i < 4; ++i) {
                const float4 v = xv[i];
                const int kl = fq * 16 + i * 4;
                Anxt[(kl + 0) * AST_ + row] = v.x;
                Anxt[(kl + 1) * AST_ + row] = v.y;
                Anxt[(kl + 2) * AST_ + row] = v.z;
                Anxt[(kl + 3) * AST_ + row] = v.w;
                sR += (v.x + v.y) + (v.z + v.w);
                qR = fmaf(v.x, v.x, fmaf(v.y, v.y,
                     fmaf(v.z, v.z, fmaf(v.w, v.w, qR))));
            }
            float4* b4 = reinterpret_cast<float4*>(Bnxt);
#pragma unroll
            for (int i = 0; i < 4; ++i) {
                float4 v = wv[i];
                v.x *= lw[i]; v.y *= lw[i]; v.z *= lw[i]; v.w *= lw[i];
                b4[i * 256 + t] = v;
            }
        }
        // ---- issue chunk c+2 global loads ----
        if (c + 2 < NCH_) {
            const int k2 = (c + 2) * BKC_;
            const float* rp = x + (size_t)(T0 + row) * C_ + k2 + fq * 16;
#pragma unroll
            for (int i = 0; i < 4; ++i) xv[i] = ld4(rp + i * 4);
            const float4* s4 = reinterpret_cast<const float4*>(
                w1 + (size_t)k2 * D_);
#pragma unroll
            for (int i = 0; i < 4; ++i) {
                wv[i] = s4[i * 256 + t];
                lw[i] = lnw[k2 + ((i * 256 + t) >> 4)];
            }
        }
        __syncthreads();   // ONE barrier per chunk
    }
    // ---- lower-stats reduce: 4 staging threads per row ----
    sR += __shfl_xor(sR, 1); qR += __shfl_xor(qR, 1);
    sR += __shfl_xor(sR, 2); qR += __shfl_xor(qR, 2);
    if (fq == 0) { sLow[row] = sR; qLow[row] = qR; }

    // ---- cross-wave acc reduce via smem (buffers dead) + P write ----
#pragma unroll
    for (int i = 0; i < 64; ++i) smem[i * 256 + t] = acc[i];
    __syncthreads();
#pragma unroll
    for (int r2 = 0; r2 < 2; ++r2) {
        const int rowO = rt * 8 + w * 2 + r2;
        float v[8];
#pragma unroll
        for (int cj = 0; cj < 8; ++cj) {
            const int i = w * 16 + r2 * 8 + cj;
            v[cj] = (smem[i * 256 + lane]
                     + smem[i * 256 + 64 + lane])
                  + (smem[i * 256 + 128 + lane]
                     + smem[i * 256 + 192 + lane]);
        }
        float* dst = Pp + (size_t)(T0 + rowO) * D_ + dt * 8;
        *reinterpret_cast<float4*>(dst) =
            make_float4(v[0], v[1], v[2], v[3]);
        *reinterpret_cast<float4*>(dst + 4) =
            make_float4(v[4], v[5], v[6], v[7]);
    }
    __syncthreads();

    // ===================== Phase U: upper stats + g-accum ==================
    float4 wvu[8], bvu[8], gacc[8];
#pragma unroll
    for (int m = 0; m < 8; ++m) {
        wvu[m] = ld4(lnw + HC_ + (m * 64 + lane) * 4);
        bvu[m] = ld4(lnb + HC_ + (m * 64 + lane) * 4);
        gacc[m] = make_float4(0.f, 0.f, 0.f, 0.f);
    }
    for (int i = 0; i < 16; ++i) {
        const int r = w * 16 + i;
        const int tok = T0 + r;
        const float* rowp = x + (size_t)tok * C_ + HC_;
        float4 v[8];
        float s = 0.f, q = 0.f;
#pragma unroll
        for (int m = 0; m < 8; ++m) {
            v[m] = ld4(rowp + (m * 64 + lane) * 4);
            s += (v[m].x + v[m].y) + (v[m].z + v[m].w);
            q = fmaf(v[m].x, v[m].x, fmaf(v[m].y, v[m].y,
                fmaf(v[m].z, v[m].z, fmaf(v[m].w, v[m].w, q))));
        }
#pragma unroll
        for (int o = 1; o < 64; o <<= 1) {
            s += __shfl_xor(s, o);
            q += __shfl_xor(q, o);
        }
        const float S_ = s + sLow[r];
        const float Q_ = q + qLow[r];
        const float mu = S_ * (1.f / C_);
        const float rs = rsqrtf(Q_ * (1.f / C_) - mu * mu + 1e-5f);
        if (lane == 0) {
            muv[tok] = mu;
            rsv[tok] = rs;
        }
#pragma unroll
        for (int m = 0; m < 8; ++m) {
            gacc[m].x += (v[m].x - mu) * rs * wvu[m].x + bvu[m].x;
            gacc[m].y += (v[m].y - mu) * rs * wvu[m].y + bvu[m].y;
            gacc[m].z += (v[m].z - mu) * rs * wvu[m].z + bvu[m].z;
            gacc[m].w += (v[m].w - mu) * rs * wvu[m].w + bvu[m].w;
        }
    }
    // cross-wave reduction via smem (sh[4][2048])
    float (*sh)[HC_] = reinterpret_cast<float(*)[HC_]>(smem);
    __syncthreads();
#pragma unroll
    for (int m = 0; m < 8; ++m)
        *reinterpret_cast<float4*>(&sh[w][(m * 64 + lane) * 4]) = gacc[m];
    __syncthreads();
    float* pp = part + (size_t)tid * HC_;
#pragma unroll
    for (int m = 0; m < 8; ++m) {
        const int j = (m * 64 + lane) * 4;
        const float4 a0 = ld4(&sh[0][j]);
        const float4 a1 = ld4(&sh[1][j]);
        const float4 a2 = ld4(&sh[2][j]);
        const float4 a3 = ld4(&sh[3][j]);
        float4 r;
        r.x = (a0.x + a1.x) + (a2.x + a3.x);
        r.y = (a0.y + a1.y) + (a2.y + a3.y);
        r.z = (a0.z + a1.z) + (a2.z + a3.z);
        r.w = (a0.w + a1.w) + (a2.w + a3.w);
        if (w == (m & 3))    // spread the 8 stores across the 4 waves
            *reinterpret_cast<float4*>(pp + j) = r;
    }
}

// ---------------------------------------------------------------------------
// K2a: fold partial-reduce + partial GEMVs.  grid 264, block 256.
// ---------------------------------------------------------------------------
__global__ __launch_bounds__(256) void k2a_part(
        const float* __restrict__ part, const float* __restrict__ w1,
        const float* __restrict__ lnw, const float* __restrict__ lnb,
        float* __restrict__ gpart, float* __restrict__ Wpart,
        float* __restrict__ Bpart) {
    __shared__ float Gs[256];
    __shared__ float red[512];
    const int t = threadIdx.x;
    const int d = t & 63, s = t >> 6;
    const int blk = blockIdx.x;
    if (blk < 256) {
        const int b = blk >> 3, jq = blk & 7;
        const int j = jq * 256 + t;
        float a = 0.f;
        for (int k = 0; k < 16; ++k)
            a += part[(size_t)(b * 16 + k) * HC_ + j];
        Gs[t] = a;
        __syncthreads();
        float acc = 0.f;
        const int j0 = jq * 256 + s * 64;
        for (int jj = 0; jj < 64; ++jj)
            acc = fmaf(Gs[s * 64 + jj],
                       w1[(size_t)(HC_ + j0 + jj) * D_ + d], acc);
        red[s * 64 + d] = acc;
        __syncthreads();
        if (s == 0)
            gpart[(size_t)blk * 64 + d] =
                red[d] + red[64 + d] + red[128 + d] + red[192 + d];
    } else {
        const int wq = blk - 256;
        const int c0 = wq * 256 + s * 64;
        float a = 0.f, c2 = 0.f;
        for (int c = c0; c < c0 + 64; ++c) {
            const float wvv = w1[(size_t)c * D_ + d];
            a = fmaf(lnw[c], wvv, a);
            c2 = fmaf(lnb[c], wvv, c2);
        }
        red[s * 64 + d] = a;
        red[256 + s * 64 + d] = c2;
        __syncthreads();
        if (s == 0) {
            Wpart[wq * 64 + d] =
                red[d] + red[64 + d] + red[128 + d] + red[192 + d];
            Bpart[wq * 64 + d] = red[256 + d] + red[320 + d]
                               + red[384 + d] + red[448 + d];
        }
    }
}

// ---------------------------------------------------------------------------
// K45: decision (k2b folded) + masked copy.  One wave per token.
// Dropped tokens write zeros WITHOUT reading x.  grid 8192, block 256.
// ---------------------------------------------------------------------------
__global__ __launch_bounds__(256) void k45_decide_mask(
        const float* __restrict__ Pp, const float* __restrict__ muv,
        const float* __restrict__ rsv, const float* __restrict__ gpart,
        const float* __restrict__ Wpart, const float* __restrict__ Bpart,
        const float* __restrict__ b1, const float* __restrict__ w2,
        const float* __restrict__ b2, const float* __restrict__ gum,
        const float* __restrict__ x, float* __restrict__ out) {
    const int t = threadIdx.x;
    const int lane = t & 63, w = t >> 6;
    const int token = blockIdx.x * 4 + w;
    const int b = token >> 10;

    // ---- folded k2b: W1s/Bs/gterm for this lane (L2-hot) ----
    float W1 = 0.f, Bsv = 0.f, gt = 0.f;
#pragma unroll
    for (int q = 0; q < 8; ++q) {
        W1 += Wpart[q * 64 + lane];
        Bsv += Bpart[q * 64 + lane];
        gt += gpart[(size_t)(b * 8 + q) * 64 + lane];
    }
    gt *= (1.f / N_);

    const float2 gv = *reinterpret_cast<const float2*>(gum + token * 2);
    const float p = Pp[(size_t)token * D_ + lane];
    const float mu = muv[token], rs = rsv[token];
    float h = rs * (p - mu * W1) + Bsv + gt + b1[lane];
    h = 0.5f * h * (1.f + erff(h * 0.70710678118654752f));   // exact gelu
    const float2 w2v = *reinterpret_cast<const float2*>(w2 + lane * 2);
    float l0 = h * w2v.x;
    float l1 = h * w2v.y;
#pragma unroll
    for (int o = 1; o < 64; o <<= 1) {
        l0 += __shfl_xor(l0, o);
        l1 += __shfl_xor(l1, o);
    }
    const float z0 = l0 + b2[0] + gv.x;
    const float z1 = l1 + b2[1] + gv.y;

    float4* dst = reinterpret_cast<float4*>(out + (size_t)token * C_);
    if (z0 >= z1) {    // keep (argmax ties -> index 0): copy x
        const float4* src =
            reinterpret_cast<const float4*>(x + (size_t)token * C_);
#pragma unroll
        for (int c = 0; c < 16; ++c)
            dst[c * 64 + lane] = src[c * 64 + lane];
    } else {           // drop: write zeros, skip the x read
        const float4 z = make_float4(0.f, 0.f, 0.f, 0.f);
#pragma unroll
        for (int c = 0; c < 16; ++c)
            dst[c * 64 + lane] = z;
    }
}

// ---------------------------------------------------------------------------
extern "C" void kernel_launch(void* const* d_in, const int* in_sizes, int n_in,
                              void* d_out, int out_size, void* d_ws,
                              size_t ws_size, hipStream_t stream) {
    const float* x   = (const float*)d_in[0];
    const float* gum = (const float*)d_in[1];
    const float* lnw = (const float*)d_in[2];
    const float* lnb = (const float*)d_in[3];
    const float* w1  = (const float*)d_in[4];
    const float* b1  = (const float*)d_in[5];
    const float* w2  = (const float*)d_in[6];
    const float* b2  = (const float*)d_in[7];
    float* out = (float*)d_out;

    float* wsf   = (float*)d_ws;
    float* Pp    = wsf;                                   // 32768*64
    float* muv   = Pp + (size_t)NT_ * D_;                 // 32768
    float* rsv   = muv + NT_;                             // 32768
    float* part  = rsv + NT_;                             // 512*2048
    float* gpart = part + (size_t)512 * HC_;              // 256*64
    float* Wpart = gpart + 256 * 64;                      // 8*64
    float* Bpart = Wpart + 8 * 64;                        // 8*64

    mk1<<<512, 256, 0, stream>>>(x, lnw, lnb, w1, Pp, muv, rsv, part);
    k2a_part<<<264, 256, 0, stream>>>(part, w1, lnw, lnb,
                                      gpart, Wpart, Bpart);
    k45_decide_mask<<<NT_ / 4, 256, 0, stream>>>(Pp, muv, rsv, gpart,
                                                 Wpart, Bpart, b1, w2, b2,
                                                 gum, x, out);
}

// Round 26
// 334.118 us; speedup vs baseline: 1.0626x; 1.0081x over previous
//
#include <hip/hip_runtime.h>
#include <math.h>

#define B_   32
#define N_   1024
#define C_   4096
#define HC_  2048
#define D_   64
#define NT_  32768           // B*N tokens
#define BKC_ 32              // K-chunk (double-buffered)
#define NCH_ (HC_ / BKC_)    // 64 chunks
#define AST_ 68              // As row stride (64 rows + 4 pad)
#define BUF_ 4224            // floats per LDS buffer (As 2176 + Bs 2048)

__device__ __forceinline__ float4 ld4(const float* p) {
    return *reinterpret_cast<const float4*>(p);
}

// ---------------------------------------------------------------------------
// MK1 v11: r25 dbuf structure at BKC=32 -> LDS 33.8 KB -> 4 blocks/CU
// (2x occupancy; dbuf already covers the shallower staging depth).
// grid 512 (M64 tiles), block 256.
// Per iteration: FMA(c) from buf[c&1] || ds_write(c+1)->buf[(c+1)&1]
// (+stats) || issue loads(c+2); ONE barrier.  G tiles: 8r x 8d (acc[64]),
// k-split across waves (wave w owns k in [w*8,(w+1)*8) of each 32-chunk).
// acc-reduce in TWO 32-KB LDS rounds (r22-verified code).
// Phase U: r25-verbatim.
// ---------------------------------------------------------------------------
__global__ __launch_bounds__(256) void mk1(
        const float* __restrict__ x, const float* __restrict__ lnw,
        const float* __restrict__ lnb, const float* __restrict__ w1,
        float* __restrict__ Pp, float* __restrict__ muv,
        float* __restrict__ rsv, float* __restrict__ part) {
    __shared__ float smem[8448];       // 33.8 KB: 2 x (As[32][68]+Bs[32][64])
    __shared__ float sLow[64], qLow[64];

    const int t = threadIdx.x;
    const int tid = blockIdx.x;
    const int T0 = tid * 64;
    const int row = t >> 2;            // staging row (0..63)
    const int fq = t & 3;              // staging k-block (8 cols each)
    const int lane = t & 63, w = t >> 6;
    const int rt = lane >> 3, dt = lane & 7;   // 8x8 FMA tile coords

    // ===================== Phase G: GEMM + lower stats =====================
    float acc[64];
#pragma unroll
    for (int i = 0; i < 64; ++i) acc[i] = 0.f;
    float sR = 0.f, qR = 0.f;

    float4 xv[2];                      // next-chunk x regs (8 cols)
    float4 wv[2];                      // next-chunk w1 regs
    float lw[2];

    {   // prologue: load chunk 0; stage -> buf0; load chunk 1
        const float* rp = x + (size_t)(T0 + row) * C_ + fq * 8;
        xv[0] = ld4(rp);
        xv[1] = ld4(rp + 4);
        const float4* s4 = reinterpret_cast<const float4*>(w1);
#pragma unroll
        for (int i = 0; i < 2; ++i) {
            wv[i] = s4[i * 256 + t];
            lw[i] = lnw[(i * 256 + t) >> 4];
        }
        float* A0 = smem;
        float* B0 = smem + 2176;
#pragma unroll
        for (int i = 0; i < 2; ++i) {
            const float4 v = xv[i];
            const int kl = fq * 8 + i * 4;
            A0[(kl + 0) * AST_ + row] = v.x;
            A0[(kl + 1) * AST_ + row] = v.y;
            A0[(kl + 2) * AST_ + row] = v.z;
            A0[(kl + 3) * AST_ + row] = v.w;
            sR += (v.x + v.y) + (v.z + v.w);
            qR = fmaf(v.x, v.x, fmaf(v.y, v.y,
                 fmaf(v.z, v.z, fmaf(v.w, v.w, qR))));
        }
        {
            float4* b4 = reinterpret_cast<float4*>(B0);
#pragma unroll
            for (int i = 0; i < 2; ++i) {
                float4 v = wv[i];
                v.x *= lw[i]; v.y *= lw[i]; v.z *= lw[i]; v.w *= lw[i];
                b4[i * 256 + t] = v;
            }
        }
        // load chunk 1 regs
        const float* rp1 = x + (size_t)(T0 + row) * C_ + BKC_ + fq * 8;
        xv[0] = ld4(rp1);
        xv[1] = ld4(rp1 + 4);
        const float4* s41 = reinterpret_cast<const float4*>(
            w1 + (size_t)BKC_ * D_);
#pragma unroll
        for (int i = 0; i < 2; ++i) {
            wv[i] = s41[i * 256 + t];
            lw[i] = lnw[BKC_ + ((i * 256 + t) >> 4)];
        }
        __syncthreads();
    }

#pragma unroll 1
    for (int c = 0; c < NCH_; ++c) {
        float* Acur = smem + (c & 1) * BUF_;
        float* Bcur = Acur + 2176;
        float* Anxt = smem + ((c + 1) & 1) * BUF_;
        float* Bnxt = Anxt + 2176;

        // ---- FMA(c): wave w owns its 8-k slice; 4 b128 per 64 FMA ----
#pragma unroll
        for (int kk = 0; kk < 8; ++kk) {
            const int k = w * 8 + kk;
            const float4 a0 = *reinterpret_cast<const float4*>(
                Acur + k * AST_ + rt * 8);
            const float4 a1 = *reinterpret_cast<const float4*>(
                Acur + k * AST_ + rt * 8 + 4);
            const float4 b0 = *reinterpret_cast<const float4*>(
                Bcur + k * 64 + dt * 8);
            const float4 b1 = *reinterpret_cast<const float4*>(
                Bcur + k * 64 + dt * 8 + 4);
            const float av[8] = {a0.x, a0.y, a0.z, a0.w,
                                 a1.x, a1.y, a1.z, a1.w};
            const float bv[8] = {b0.x, b0.y, b0.z, b0.w,
                                 b1.x, b1.y, b1.z, b1.w};
#pragma unroll
            for (int ri = 0; ri < 8; ++ri)
#pragma unroll
                for (int cj = 0; cj < 8; ++cj)
                    acc[ri * 8 + cj] =
                        fmaf(av[ri], bv[cj], acc[ri * 8 + cj]);
        }
        // ---- ds_write chunk c+1 -> other buffer (+stats) ----
        if (c + 1 < NCH_) {
#pragma unroll
            for (int i = 0; i < 2; ++i) {
                const float4 v = xv[i];
                const int kl = fq * 8 + i * 4;
                Anxt[(kl + 0) * AST_ + row] = v.x;
                Anxt[(kl + 1) * AST_ + row] = v.y;
                Anxt[(kl + 2) * AST_ + row] = v.z;
                Anxt[(kl + 3) * AST_ + row] = v.w;
                sR += (v.x + v.y) + (v.z + v.w);
                qR = fmaf(v.x, v.x, fmaf(v.y, v.y,
                     fmaf(v.z, v.z, fmaf(v.w, v.w, qR))));
            }
            float4* b4 = reinterpret_cast<float4*>(Bnxt);
#pragma unroll
            for (int i = 0; i < 2; ++i) {
                float4 v = wv[i];
                v.x *= lw[i]; v.y *= lw[i]; v.z *= lw[i]; v.w *= lw[i];
                b4[i * 256 + t] = v;
            }
        }
        // ---- issue chunk c+2 global loads ----
        if (c + 2 < NCH_) {
            const int k2 = (c + 2) * BKC_;
            const float* rp = x + (size_t)(T0 + row) * C_ + k2 + fq * 8;
            xv[0] = ld4(rp);
            xv[1] = ld4(rp + 4);
            const float4* s4 = reinterpret_cast<const float4*>(
                w1 + (size_t)k2 * D_);
#pragma unroll
            for (int i = 0; i < 2; ++i) {
                wv[i] = s4[i * 256 + t];
                lw[i] = lnw[k2 + ((i * 256 + t) >> 4)];
            }
        }
        __syncthreads();   // ONE barrier per chunk
    }
    // ---- lower-stats reduce: 4 staging threads per row ----
    sR += __shfl_xor(sR, 1); qR += __shfl_xor(qR, 1);
    sR += __shfl_xor(sR, 2); qR += __shfl_xor(qR, 2);
    if (fq == 0) { sLow[row] = sR; qLow[row] = qR; }

    // ---- cross-wave acc reduce via smem, TWO 32-KB rounds + P write ----
#pragma unroll
    for (int h = 0; h < 2; ++h) {
#pragma unroll
        for (int i = 0; i < 32; ++i) smem[i * 256 + t] = acc[h * 32 + i];
        __syncthreads();
        if ((w >> 1) == h) {          // waves 2h, 2h+1 read this round
#pragma unroll
            for (int r2 = 0; r2 < 2; ++r2) {
                const int rowO = rt * 8 + w * 2 + r2;
                float v[8];
#pragma unroll
                for (int cj = 0; cj < 8; ++cj) {
                    const int i = (w - 2 * h) * 16 + r2 * 8 + cj;
                    v[cj] = (smem[i * 256 + lane]
                             + smem[i * 256 + 64 + lane])
                          + (smem[i * 256 + 128 + lane]
                             + smem[i * 256 + 192 + lane]);
                }
                float* dst = Pp + (size_t)(T0 + rowO) * D_ + dt * 8;
                *reinterpret_cast<float4*>(dst) =
                    make_float4(v[0], v[1], v[2], v[3]);
                *reinterpret_cast<float4*>(dst + 4) =
                    make_float4(v[4], v[5], v[6], v[7]);
            }
        }
        __syncthreads();
    }

    // ===================== Phase U: upper stats + g-accum ==================
    float4 wvu[8], bvu[8], gacc[8];
#pragma unroll
    for (int m = 0; m < 8; ++m) {
        wvu[m] = ld4(lnw + HC_ + (m * 64 + lane) * 4);
        bvu[m] = ld4(lnb + HC_ + (m * 64 + lane) * 4);
        gacc[m] = make_float4(0.f, 0.f, 0.f, 0.f);
    }
    for (int i = 0; i < 16; ++i) {
        const int r = w * 16 + i;
        const int tok = T0 + r;
        const float* rowp = x + (size_t)tok * C_ + HC_;
        float4 v[8];
        float s = 0.f, q = 0.f;
#pragma unroll
        for (int m = 0; m < 8; ++m) {
            v[m] = ld4(rowp + (m * 64 + lane) * 4);
            s += (v[m].x + v[m].y) + (v[m].z + v[m].w);
            q = fmaf(v[m].x, v[m].x, fmaf(v[m].y, v[m].y,
                fmaf(v[m].z, v[m].z, fmaf(v[m].w, v[m].w, q))));
        }
#pragma unroll
        for (int o = 1; o < 64; o <<= 1) {
            s += __shfl_xor(s, o);
            q += __shfl_xor(q, o);
        }
        const float S_ = s + sLow[r];
        const float Q_ = q + qLow[r];
        const float mu = S_ * (1.f / C_);
        const float rs = rsqrtf(Q_ * (1.f / C_) - mu * mu + 1e-5f);
        if (lane == 0) {
            muv[tok] = mu;
            rsv[tok] = rs;
        }
#pragma unroll
        for (int m = 0; m < 8; ++m) {
            gacc[m].x += (v[m].x - mu) * rs * wvu[m].x + bvu[m].x;
            gacc[m].y += (v[m].y - mu) * rs * wvu[m].y + bvu[m].y;
            gacc[m].z += (v[m].z - mu) * rs * wvu[m].z + bvu[m].z;
            gacc[m].w += (v[m].w - mu) * rs * wvu[m].w + bvu[m].w;
        }
    }
    // cross-wave reduction via smem (sh[4][2048] = 32 KB, fits 33.8)
    float (*sh)[HC_] = reinterpret_cast<float(*)[HC_]>(smem);
    __syncthreads();
#pragma unroll
    for (int m = 0; m < 8; ++m)
        *reinterpret_cast<float4*>(&sh[w][(m * 64 + lane) * 4]) = gacc[m];
    __syncthreads();
    float* pp = part + (size_t)tid * HC_;
#pragma unroll
    for (int m = 0; m < 8; ++m) {
        const int j = (m * 64 + lane) * 4;
        const float4 a0 = ld4(&sh[0][j]);
        const float4 a1 = ld4(&sh[1][j]);
        const float4 a2 = ld4(&sh[2][j]);
        const float4 a3 = ld4(&sh[3][j]);
        float4 r;
        r.x = (a0.x + a1.x) + (a2.x + a3.x);
        r.y = (a0.y + a1.y) + (a2.y + a3.y);
        r.z = (a0.z + a1.z) + (a2.z + a3.z);
        r.w = (a0.w + a1.w) + (a2.w + a3.w);
        if (w == (m & 3))    // spread the 8 stores across the 4 waves
            *reinterpret_cast<float4*>(pp + j) = r;
    }
}

// ---------------------------------------------------------------------------
// K2a: fold partial-reduce + partial GEMVs.  grid 264, block 256.
// ---------------------------------------------------------------------------
__global__ __launch_bounds__(256) void k2a_part(
        const float* __restrict__ part, const float* __restrict__ w1,
        const float* __restrict__ lnw, const float* __restrict__ lnb,
        float* __restrict__ gpart, float* __restrict__ Wpart,
        float* __restrict__ Bpart) {
    __shared__ float Gs[256];
    __shared__ float red[512];
    const int t = threadIdx.x;
    const int d = t & 63, s = t >> 6;
    const int blk = blockIdx.x;
    if (blk < 256) {
        const int b = blk >> 3, jq = blk & 7;
        const int j = jq * 256 + t;
        float a = 0.f;
        for (int k = 0; k < 16; ++k)
            a += part[(size_t)(b * 16 + k) * HC_ + j];
        Gs[t] = a;
        __syncthreads();
        float acc = 0.f;
        const int j0 = jq * 256 + s * 64;
        for (int jj = 0; jj < 64; ++jj)
            acc = fmaf(Gs[s * 64 + jj],
                       w1[(size_t)(HC_ + j0 + jj) * D_ + d], acc);
        red[s * 64 + d] = acc;
        __syncthreads();
        if (s == 0)
            gpart[(size_t)blk * 64 + d] =
                red[d] + red[64 + d] + red[128 + d] + red[192 + d];
    } else {
        const int wq = blk - 256;
        const int c0 = wq * 256 + s * 64;
        float a = 0.f, c2 = 0.f;
        for (int c = c0; c < c0 + 64; ++c) {
            const float wvv = w1[(size_t)c * D_ + d];
            a = fmaf(lnw[c], wvv, a);
            c2 = fmaf(lnb[c], wvv, c2);
        }
        red[s * 64 + d] = a;
        red[256 + s * 64 + d] = c2;
        __syncthreads();
        if (s == 0) {
            Wpart[wq * 64 + d] =
                red[d] + red[64 + d] + red[128 + d] + red[192 + d];
            Bpart[wq * 64 + d] = red[256 + d] + red[320 + d]
                               + red[384 + d] + red[448 + d];
        }
    }
}

// ---------------------------------------------------------------------------
// K45: decision (k2b folded) + masked copy.  One wave per token.
// Dropped tokens write zeros WITHOUT reading x.  grid 8192, block 256.
// ---------------------------------------------------------------------------
__global__ __launch_bounds__(256) void k45_decide_mask(
        const float* __restrict__ Pp, const float* __restrict__ muv,
        const float* __restrict__ rsv, const float* __restrict__ gpart,
        const float* __restrict__ Wpart, const float* __restrict__ Bpart,
        const float* __restrict__ b1, const float* __restrict__ w2,
        const float* __restrict__ b2, const float* __restrict__ gum,
        const float* __restrict__ x, float* __restrict__ out) {
    const int t = threadIdx.x;
    const int lane = t & 63, w = t >> 6;
    const int token = blockIdx.x * 4 + w;
    const int b = token >> 10;

    // ---- folded k2b: W1s/Bs/gterm for this lane (L2-hot) ----
    float W1 = 0.f, Bsv = 0.f, gt = 0.f;
#pragma unroll
    for (int q = 0; q < 8; ++q) {
        W1 += Wpart[q * 64 + lane];
        Bsv += Bpart[q * 64 + lane];
        gt += gpart[(size_t)(b * 8 + q) * 64 + lane];
    }
    gt *= (1.f / N_);

    const float2 gv = *reinterpret_cast<const float2*>(gum + token * 2);
    const float p = Pp[(size_t)token * D_ + lane];
    const float mu = muv[token], rs = rsv[token];
    float h = rs * (p - mu * W1) + Bsv + gt + b1[lane];
    h = 0.5f * h * (1.f + erff(h * 0.70710678118654752f));   // exact gelu
    const float2 w2v = *reinterpret_cast<const float2*>(w2 + lane * 2);
    float l0 = h * w2v.x;
    float l1 = h * w2v.y;
#pragma unroll
    for (int o = 1; o < 64; o <<= 1) {
        l0 += __shfl_xor(l0, o);
        l1 += __shfl_xor(l1, o);
    }
    const float z0 = l0 + b2[0] + gv.x;
    const float z1 = l1 + b2[1] + gv.y;

    float4* dst = reinterpret_cast<float4*>(out + (size_t)token * C_);
    if (z0 >= z1) {    // keep (argmax ties -> index 0): copy x
        const float4* src =
            reinterpret_cast<const float4*>(x + (size_t)token * C_);
#pragma unroll
        for (int c = 0; c < 16; ++c)
            dst[c * 64 + lane] = src[c * 64 + lane];
    } else {           // drop: write zeros, skip the x read
        const float4 z = make_float4(0.f, 0.f, 0.f, 0.f);
#pragma unroll
        for (int c = 0; c < 16; ++c)
            dst[c * 64 + lane] = z;
    }
}

// ---------------------------------------------------------------------------
extern "C" void kernel_launch(void* const* d_in, const int* in_sizes, int n_in,
                              void* d_out, int out_size, void* d_ws,
                              size_t ws_size, hipStream_t stream) {
    const float* x   = (const float*)d_in[0];
    const float* gum = (const float*)d_in[1];
    const float* lnw = (const float*)d_in[2];
    const float* lnb = (const float*)d_in[3];
    const float* w1  = (const float*)d_in[4];
    const float* b1  = (const float*)d_in[5];
    const float* w2  = (const float*)d_in[6];
    const float* b2  = (const float*)d_in[7];
    float* out = (float*)d_out;

    float* wsf   = (float*)d_ws;
    float* Pp    = wsf;                                   // 32768*64
    float* muv   = Pp + (size_t)NT_ * D_;                 // 32768
    float* rsv   = muv + NT_;                             // 32768
    float* part  = rsv + NT_;                             // 512*2048
    float* gpart = part + (size_t)512 * HC_;              // 256*64
    float* Wpart = gpart + 256 * 64;                      // 8*64
    float* Bpart = Wpart + 8 * 64;                        // 8*64

    mk1<<<512, 256, 0, stream>>>(x, lnw, lnb, w1, Pp, muv, rsv, part);
    k2a_part<<<264, 256, 0, stream>>>(part, w1, lnw, lnb,
                                      gpart, Wpart, Bpart);
    k45_decide_mask<<<NT_ / 4, 256, 0, stream>>>(Pp, muv, rsv, gpart,
                                                 Wpart, Bpart, b1, w2, b2,
                                                 gum, x, out);
}